// Round 6
// baseline (74.310 us; speedup 1.0000x reference)
//
#include <hip/hip_runtime.h>

// Sparsegen (sigma=0 => sparsemax) along last dim of a [32768, 2048] f32 tensor.
// TWO rows per 64-lane wave (R6): 16 outstanding HBM loads per wave instead of
// 8, and row B's compute/stores overlap row A's — attacks the ~12% gap to the
// mixed-stream HBM ceiling (403 MB @ 5.6 TB/s = 72 us; floor ~64 us).
//
// Michelot in ORIGINAL coordinates: T' = (sum_{x>T} x - 1)/cnt from the tight
// bound T0 = m - 1 (tau* >= -1); monotone from below, wave-uniform break.
// Count via ballot+popcount (SALU pipe); sums via DPP butterflies (pure VALU);
// epilogue saturate(x - T) (sparsemax outputs are in [0,1]); nt stores keep
// the L3 for the input (which is exactly L3-sized -> ~50% replay hit rate).

#define N_COLS 2048

typedef float floatx4 __attribute__((ext_vector_type(4)));

template <int CTRL, int ROW_MASK, bool BC0>
__device__ __forceinline__ float dpp_f(float old_, float src) {
    int r = __builtin_amdgcn_update_dpp(
        __builtin_bit_cast(int, old_), __builtin_bit_cast(int, src),
        CTRL, ROW_MASK, 0xf, BC0);
    return __builtin_bit_cast(float, r);
}

__device__ __forceinline__ float bcast63(float x) {
    return __builtin_bit_cast(float,
        __builtin_amdgcn_readlane(__builtin_bit_cast(int, x), 63));
}

__device__ __forceinline__ float wave_sum(float x) {
    x += dpp_f<0x111, 0xf, true>(0.0f, x);  // row_shr:1
    x += dpp_f<0x112, 0xf, true>(0.0f, x);  // row_shr:2
    x += dpp_f<0x114, 0xf, true>(0.0f, x);  // row_shr:4
    x += dpp_f<0x118, 0xf, true>(0.0f, x);  // row_shr:8
    x += dpp_f<0x142, 0xa, true>(0.0f, x);  // row_bcast15
    x += dpp_f<0x143, 0xc, true>(0.0f, x);  // row_bcast31 -> lane63
    return bcast63(x);
}

__device__ __forceinline__ float wave_max(float x) {
    x = fmaxf(x, dpp_f<0x111, 0xf, false>(x, x));
    x = fmaxf(x, dpp_f<0x112, 0xf, false>(x, x));
    x = fmaxf(x, dpp_f<0x114, 0xf, false>(x, x));
    x = fmaxf(x, dpp_f<0x118, 0xf, false>(x, x));
    x = fmaxf(x, dpp_f<0x142, 0xa, false>(x, x));
    x = fmaxf(x, dpp_f<0x143, 0xc, false>(x, x));
    return bcast63(x);
}

// Solve tau for one row held in v[8]; returns T with out = saturate(x - T).
__device__ __forceinline__ float michelot(const floatx4* v) {
    float m = -INFINITY;
#pragma unroll
    for (int j = 0; j < 8; ++j)
        m = fmaxf(m, fmaxf(fmaxf(v[j].x, v[j].y), fmaxf(v[j].z, v[j].w)));
    m = wave_max(m);

    float T = m - 1.0f;
    for (int it = 0; it < 32; ++it) {
        float p0 = 0.0f, p1 = 0.0f, p2 = 0.0f, p3 = 0.0f;
        int cnt = 0;  // wave-uniform (ballot popcounts, SALU pipe)
#pragma unroll
        for (int j = 0; j < 8; ++j) {
            bool gx = v[j].x > T, gy = v[j].y > T,
                 gz = v[j].z > T, gw = v[j].w > T;
            p0 += gx ? v[j].x : 0.0f;
            p1 += gy ? v[j].y : 0.0f;
            p2 += gz ? v[j].z : 0.0f;
            p3 += gw ? v[j].w : 0.0f;
            cnt += __popcll(__ballot(gx));
            cnt += __popcll(__ballot(gy));
            cnt += __popcll(__ballot(gz));
            cnt += __popcll(__ballot(gw));
        }
        float ps = wave_sum((p0 + p1) + (p2 + p3));
        float newT = (ps - 1.0f) / (float)cnt;  // cnt >= 1: row max > T always
        if (!(newT > T)) break;                 // wave-uniform
        T = newT;
    }
    return T;
}

__global__ __launch_bounds__(256) void sparsemax_kernel(
    const float* __restrict__ x, float* __restrict__ out, int n_rows) {
    const int lane = threadIdx.x & 63;
    const int wave = threadIdx.x >> 6;
    const int rowA = (blockIdx.x * 4 + wave) * 2;   // two consecutive rows/wave
    if (rowA + 1 >= n_rows + 1) return;             // grid sized exactly

    const floatx4* __restrict__ xinA =
        reinterpret_cast<const floatx4*>(x + (size_t)rowA * N_COLS);
    const floatx4* __restrict__ xinB = xinA + (N_COLS / 4);
    floatx4* __restrict__ xoutA =
        reinterpret_cast<floatx4*>(out + (size_t)rowA * N_COLS);
    floatx4* __restrict__ xoutB = xoutA + (N_COLS / 4);

    // Issue BOTH rows' loads up front: 16 outstanding 16B loads per wave.
    floatx4 a[8], b[8];
#pragma unroll
    for (int j = 0; j < 8; ++j) a[j] = xinA[j * 64 + lane];
#pragma unroll
    for (int j = 0; j < 8; ++j) b[j] = xinB[j * 64 + lane];

    float TA = michelot(a);
#pragma unroll
    for (int j = 0; j < 8; ++j) {
        floatx4 o;
        o.x = __saturatef(a[j].x - TA);
        o.y = __saturatef(a[j].y - TA);
        o.z = __saturatef(a[j].z - TA);
        o.w = __saturatef(a[j].w - TA);
        __builtin_nontemporal_store(o, &xoutA[j * 64 + lane]);
    }

    float TB = michelot(b);
#pragma unroll
    for (int j = 0; j < 8; ++j) {
        floatx4 o;
        o.x = __saturatef(b[j].x - TB);
        o.y = __saturatef(b[j].y - TB);
        o.z = __saturatef(b[j].z - TB);
        o.w = __saturatef(b[j].w - TB);
        __builtin_nontemporal_store(o, &xoutB[j * 64 + lane]);
    }
}

extern "C" void kernel_launch(void* const* d_in, const int* in_sizes, int n_in,
                              void* d_out, int out_size, void* d_ws, size_t ws_size,
                              hipStream_t stream) {
    const float* x = (const float*)d_in[0];
    float* out = (float*)d_out;
    int n_rows = in_sizes[0] / N_COLS;               // 32768
    int blocks = (n_rows / 2 + 3) / 4;               // 2 rows/wave, 4 waves/block
    sparsemax_kernel<<<blocks, 256, 0, stream>>>(x, out, n_rows);
}

// Round 7
// 72.358 us; speedup vs baseline: 1.0270x; 1.0270x over previous
//
#include <hip/hip_runtime.h>

// Sparsegen (sigma=0 => sparsemax) along last dim of a [32768, 2048] f32 tensor.
// One 64-lane wave per row; 32 elements/lane in registers (8 x 4 floats).
// FINAL (revert to R5 config — fastest measured at 72.3 us):
//   R6's 2-rows/wave MLP variant regressed (74.3); TLP already covers latency.
//
// Michelot's algorithm in ORIGINAL coordinates: T' = (sum_{x>T} x - 1)/cnt
// from the tight lower bound T0 = m - 1 (tau* >= -1). Monotone from below;
// break is wave-uniform. Count via ballot+popcount (SALU pipe); sums via DPP
// butterflies (pure VALU, no DS pipe); epilogue saturate(x - T) (outputs in
// [0,1]); nt stores keep the L3 for the input (exactly L3-sized, ~50% hits).
//
// Measured bound: 403 MB HBM (131 fetch + 262 write) at 5.6 TB/s = 88% of the
// 6.29 TB/s mixed-copy ceiling; VALU/shuffle/MLP optimizations all null.

#define N_COLS 2048

typedef float floatx4 __attribute__((ext_vector_type(4)));

// dpp_ctrl / row_mask / bound_ctrl must be ICEs -> template parameters.
template <int CTRL, int ROW_MASK, bool BC0>
__device__ __forceinline__ float dpp_f(float old_, float src) {
    int r = __builtin_amdgcn_update_dpp(
        __builtin_bit_cast(int, old_), __builtin_bit_cast(int, src),
        CTRL, ROW_MASK, 0xf, BC0);
    return __builtin_bit_cast(float, r);
}

__device__ __forceinline__ float bcast63(float x) {
    return __builtin_bit_cast(float,
        __builtin_amdgcn_readlane(__builtin_bit_cast(int, x), 63));
}

// Sum across 64 lanes; result broadcast to all lanes.
// bound_ctrl=1: shifted-in lanes read 0 (identity for +).
__device__ __forceinline__ float wave_sum(float x) {
    x += dpp_f<0x111, 0xf, true>(0.0f, x);  // row_shr:1
    x += dpp_f<0x112, 0xf, true>(0.0f, x);  // row_shr:2
    x += dpp_f<0x114, 0xf, true>(0.0f, x);  // row_shr:4
    x += dpp_f<0x118, 0xf, true>(0.0f, x);  // row_shr:8  -> lane15 of each row
    x += dpp_f<0x142, 0xa, true>(0.0f, x);  // row_bcast15 -> rows 1,3
    x += dpp_f<0x143, 0xc, true>(0.0f, x);  // row_bcast31 -> lane63 = total
    return bcast63(x);
}

// Max across 64 lanes; invalid lanes keep old=x (identity for max).
__device__ __forceinline__ float wave_max(float x) {
    x = fmaxf(x, dpp_f<0x111, 0xf, false>(x, x));
    x = fmaxf(x, dpp_f<0x112, 0xf, false>(x, x));
    x = fmaxf(x, dpp_f<0x114, 0xf, false>(x, x));
    x = fmaxf(x, dpp_f<0x118, 0xf, false>(x, x));
    x = fmaxf(x, dpp_f<0x142, 0xa, false>(x, x));
    x = fmaxf(x, dpp_f<0x143, 0xc, false>(x, x));
    return bcast63(x);
}

__global__ __launch_bounds__(256) void sparsemax_kernel(
    const float* __restrict__ x, float* __restrict__ out, int n_rows) {
    const int lane = threadIdx.x & 63;
    const int wave = threadIdx.x >> 6;
    const int row  = blockIdx.x * 4 + wave;
    if (row >= n_rows) return;

    const floatx4* __restrict__ xin =
        reinterpret_cast<const floatx4*>(x + (size_t)row * N_COLS);
    floatx4* __restrict__ xout =
        reinterpret_cast<floatx4*>(out + (size_t)row * N_COLS);

    // Coalesced load: lane-contiguous 16B (wave covers the 8KB row).
    floatx4 v[8];
#pragma unroll
    for (int j = 0; j < 8; ++j) v[j] = xin[j * 64 + lane];

    // ---- row max ----
    float m = -INFINITY;
#pragma unroll
    for (int j = 0; j < 8; ++j)
        m = fmaxf(m, fmaxf(fmaxf(v[j].x, v[j].y), fmaxf(v[j].z, v[j].w)));
    m = wave_max(m);

    // ---- Michelot from the tight bound T0 = m - 1 ----
    float T = m - 1.0f;
    for (int it = 0; it < 32; ++it) {
        float p0 = 0.0f, p1 = 0.0f, p2 = 0.0f, p3 = 0.0f;
        int cnt = 0;  // wave-uniform (ballot popcounts, SALU pipe)
#pragma unroll
        for (int j = 0; j < 8; ++j) {
            bool gx = v[j].x > T, gy = v[j].y > T,
                 gz = v[j].z > T, gw = v[j].w > T;
            p0 += gx ? v[j].x : 0.0f;
            p1 += gy ? v[j].y : 0.0f;
            p2 += gz ? v[j].z : 0.0f;
            p3 += gw ? v[j].w : 0.0f;
            cnt += __popcll(__ballot(gx));
            cnt += __popcll(__ballot(gy));
            cnt += __popcll(__ballot(gz));
            cnt += __popcll(__ballot(gw));
        }
        float ps = wave_sum((p0 + p1) + (p2 + p3));
        // cnt >= 1 always: the row max satisfies m > T for all T <= T* < m.
        float newT = (ps - 1.0f) / (float)cnt;
        if (!(newT > T)) break;  // wave-uniform
        T = newT;
    }

    // ---- out = max(0, x - T) = saturate(x - T) (sparsemax outputs <= 1);
    //      non-temporal stores keep the L3 for the input ----
#pragma unroll
    for (int j = 0; j < 8; ++j) {
        floatx4 o;
        o.x = __saturatef(v[j].x - T);
        o.y = __saturatef(v[j].y - T);
        o.z = __saturatef(v[j].z - T);
        o.w = __saturatef(v[j].w - T);
        __builtin_nontemporal_store(o, &xout[j * 64 + lane]);
    }
}

extern "C" void kernel_launch(void* const* d_in, const int* in_sizes, int n_in,
                              void* d_out, int out_size, void* d_ws, size_t ws_size,
                              hipStream_t stream) {
    const float* x = (const float*)d_in[0];
    float* out = (float*)d_out;
    int n_rows = in_sizes[0] / N_COLS;           // 32768
    int blocks = (n_rows + 3) / 4;               // 4 rows (waves) per 256-thread block
    sparsemax_kernel<<<blocks, 256, 0, stream>>>(x, out, n_rows);
}